// Round 4
// baseline (184.311 us; speedup 1.0000x reference)
//
#include <hip/hip_runtime.h>

#define BB 64
#define CC 64
#define TT 4000

// ---- gram geometry ----
#define SLABS 8              // slabs per batch; grid = BB*SLABS = 512
#define TSLAB 250            // staged chunk, padded to 256 t (32 chunks of 8 bf16)
#define SLABT (2 * TSLAB)    // 500 t per block
#define GP_PITCH 264         // shorts per LDS row (16B-aligned rows, chunk 32 = pad)

// ---- apply geometry ----
#define TPB 128
#define APITCH 72            // shorts per al row (16B aligned)

// ws layout (floats): G_part[8][64][64][64] | S_part[8][64][64]
#define GPART_ELEMS ((size_t)SLABS * BB * CC * CC)

typedef short short8 __attribute__((ext_vector_type(8)));
typedef float f32x16 __attribute__((ext_vector_type(16)));

__device__ __forceinline__ short f2bf(float f) {
    unsigned u = __float_as_uint(f);
    u = (u + 0x7FFFu + ((u >> 16) & 1u)) >> 16;   // round-to-nearest-even
    return (short)u;
}
__device__ __forceinline__ float bfpair(unsigned u) {   // sum of 2 packed bf16
    return __uint_as_float(u << 16) + __uint_as_float(u & 0xFFFF0000u);
}

// ---- gram helpers (identical math to the verified R1 kernel) ----
__device__ __forceinline__ void stage_load(const float* __restrict__ xb, int t0,
                                           int g, int tid, float4 v[8]) {
    #pragma unroll
    for (int k = 0; k < 8; ++k) {
        const int i = tid + 256 * (g * 8 + k);
        const int row = i >> 6, tq = i & 63;               // t_local = 4*tq
        float4 w = make_float4(0.f, 0.f, 0.f, 0.f);
        if (tq < 62) {
            w = *(const float4*)(xb + row * TT + t0 + 4 * tq);
        } else if (tq == 62) {
            const float* p = xb + row * TT + t0 + 248;
            w.x = p[0]; w.y = p[1];
        }
        v[k] = w;
    }
}
__device__ __forceinline__ void stage_write(short* xs, int g, int tid, const float4 v[8]) {
    #pragma unroll
    for (int k = 0; k < 8; ++k) {
        const int i = tid + 256 * (g * 8 + k);
        const int row = i >> 6, tq = i & 63;
        short4 sv;
        sv.x = f2bf(v[k].x); sv.y = f2bf(v[k].y);
        sv.z = f2bf(v[k].z); sv.w = f2bf(v[k].w);
        const int pc = (tq >> 1) ^ (row & 7);              // swizzled chunk
        *(short4*)(xs + row * GP_PITCH + pc * 8 + (tq & 1) * 4) = sv;
    }
}
__device__ __forceinline__ float s_partial(const short* xs, int lane, int wave) {
    const short* rowp = xs + lane * GP_PITCH;
    float s = 0.f;
    #pragma unroll
    for (int j = 0; j < 8; ++j) {
        const int pc = (wave * 8 + j) ^ (lane & 7);
        uint2 u0 = *(const uint2*)(rowp + pc * 8);
        uint2 u1 = *(const uint2*)(rowp + pc * 8 + 4);
        s += bfpair(u0.x) + bfpair(u0.y) + bfpair(u1.x) + bfpair(u1.y);
    }
    return s;
}
__device__ __forceinline__ void mfma_tile(const short* xs, int r0, int c0,
                                          int m, int half, f32x16& acc) {
    #pragma unroll
    for (int ks = 0; ks < 16; ++ks) {
        const int ck = ks * 2 + half;                      // logical 8-short chunk of k
        short8 av = *(const short8*)(xs + (r0 + m) * GP_PITCH + (ck ^ (m & 7)) * 8);
        short8 bv = *(const short8*)(xs + (c0 + m) * GP_PITCH + (ck ^ (m & 7)) * 8);
        acc = __builtin_amdgcn_mfma_f32_32x32x16_bf16(av, bv, acc, 0, 0, 0);
    }
}

// G_part[s][b][r][c] = sum_{t in slab} x[b][r][t]*x[b][c][t]; S_part likewise.
// Double-buffered: chunk-1 global loads issued before chunk-0 compute (T14).
__global__ __launch_bounds__(256)
void gram_mfma(const float* __restrict__ x, float* __restrict__ G_part,
               float* __restrict__ S_part) {
    __shared__ short xs[2][CC * GP_PITCH];   // 2 x 33.8 KB bf16
    __shared__ float sred[4 * 64];
    const int b    = blockIdx.x / SLABS;
    const int slab = blockIdx.x % SLABS;
    const int tid  = threadIdx.x;
    const int lane = tid & 63;
    const int wave = tid >> 6;
    const float* xb = x + (size_t)b * CC * TT;

    const int r0 = (wave >> 1) * 32, c0 = (wave & 1) * 32;
    const int m = lane & 31, half = lane >> 5;
    f32x16 acc;
    #pragma unroll
    for (int z = 0; z < 16; ++z) acc[z] = 0.f;

    const int t0a = slab * SLABT, t0b = t0a + TSLAB;

    // stage chunk 0 into xs[0]
    {
        float4 v[8];
        stage_load(xb, t0a, 0, tid, v);
        stage_write(xs[0], 0, tid, v);
        stage_load(xb, t0a, 1, tid, v);
        stage_write(xs[0], 1, tid, v);
    }
    __syncthreads();

    // prefetch chunk 1 into registers (latency hides under chunk-0 compute)
    float4 p0[8], p1[8];
    stage_load(xb, t0b, 0, tid, p0);
    stage_load(xb, t0b, 1, tid, p1);

    // compute chunk 0
    float s_acc = s_partial(xs[0], lane, wave);
    mfma_tile(xs[0], r0, c0, m, half, acc);

    // write chunk 1 (compiler waits on the prefetch loads here)
    stage_write(xs[1], 0, tid, p0);
    stage_write(xs[1], 1, tid, p1);
    __syncthreads();

    // compute chunk 1
    s_acc += s_partial(xs[1], lane, wave);
    mfma_tile(xs[1], r0, c0, m, half, acc);

    sred[wave * 64 + lane] = s_acc;
    __syncthreads();
    if (tid < 64) {
        float s = sred[tid] + sred[64 + tid] + sred[128 + tid] + sred[192 + tid];
        S_part[(slab * BB + b) * CC + tid] = s;
    }
    float* gp = G_part + ((size_t)slab * BB + b) * (CC * CC);
    #pragma unroll
    for (int r = 0; r < 16; ++r) {
        const int row = (r & 3) + 8 * (r >> 2) + 4 * half;
        gp[(r0 + row) * CC + (c0 + m)] = acc[r];
    }
}

// Kernel 2: 512 blocks = (slab, b). Each block redundantly computes its batch's
// softmax into LDS al = P^T (bf16), hoists its P^T fragments into registers,
// then applies out = gamma * P^T x + x with a BARRIER-FREE loop that reads x
// fragments and the residual straight from global (LLC-hot after kernel 1).
__global__ __launch_bounds__(256)
void softmax_apply(const float* __restrict__ x,
                   const float* __restrict__ w1, const float* __restrict__ b1,
                   const float* __restrict__ w2, const float* __restrict__ b2,
                   const float* __restrict__ G_part, const float* __restrict__ S_part,
                   const float* __restrict__ gamma, float* __restrict__ out) {
    __shared__ float Es[64 * 65];         // 16.6 KB
    __shared__ short al[CC * APITCH];     // 9.2 KB:  al[X][Y] = P[Y][X] (bf16)
    __shared__ float red[3 * 256];
    __shared__ float Sb[64];
    const int tid  = threadIdx.x;
    const int lane = tid & 63, wave = tid >> 6;
    const int b    = blockIdx.x & 63;
    const int slab = blockIdx.x >> 6;
    const float* xb = x + (size_t)b * CC * TT;
    const int m = lane & 31, half = lane >> 5;

    // ---------- phase A: softmax for batch b ----------
    {
        #pragma unroll
        for (int j4 = 0; j4 < 4; ++j4) {
            const int jj = tid + 256 * j4;                 // float4 index 0..1023
            float4 s = make_float4(0.f, 0.f, 0.f, 0.f);
            #pragma unroll
            for (int sl = 0; sl < SLABS; ++sl) {
                const float4 g = *(const float4*)(G_part + ((size_t)sl * BB + b) * 4096 + 4 * jj);
                s.x += g.x; s.y += g.y; s.z += g.z; s.w += g.w;
            }
            const int row = jj >> 4, col = (jj & 15) * 4;
            float* e = Es + row * 65 + col;
            e[0] = s.x; e[1] = s.y; e[2] = s.z; e[3] = s.w;
        }
        if (tid < 64) {
            float s = 0.f;
            #pragma unroll
            for (int sl = 0; sl < SLABS; ++sl)
                s += S_part[(sl * BB + b) * CC + tid];
            Sb[tid] = s;
        }
        float A = 0.f, Bc = 0.f, Be = 0.f, Cc = 0.f;
        #pragma unroll
        for (int j = 0; j < 8; ++j) {
            float a1 = w1[j], a2 = w2[j], q1 = b1[j], q2 = b2[j];
            A += a1 * a2; Bc += a1 * q2; Be += q1 * a2; Cc += q1 * q2;
        }
        Cc *= (float)TT;
        __syncthreads();

        const int c = tid & 63, q = tid >> 6;
        const float sc = Sb[c];
        float ev[16], mn = 1e30f, mx = -1e30f;
        #pragma unroll
        for (int i = 0; i < 16; ++i) {
            const int e = 16 * q + i;
            float en = A * Es[c * 65 + e] + Bc * sc + Be * Sb[e] + Cc;
            ev[i] = en;
            mn = fminf(mn, en); mx = fmaxf(mx, en);
        }
        red[q * 64 + c] = mn; red[256 + q * 64 + c] = mx;
        __syncthreads();
        mn = fminf(fminf(red[c], red[64 + c]), fminf(red[128 + c], red[192 + c]));
        mx = fmaxf(fmaxf(red[256 + c], red[320 + c]), fmaxf(red[384 + c], red[448 + c]));
        const float ninv = 1.f / (mx - mn + 1e-8f);
        float pv[16], ls = 0.f;
        #pragma unroll
        for (int i = 0; i < 16; ++i) {
            float p = __expf((ev[i] - mn) * ninv);
            pv[i] = p; ls += p;
        }
        red[512 + q * 64 + c] = ls;
        __syncthreads();
        const float rinv = 1.f / (red[512 + c] + red[576 + c] + red[640 + c] + red[704 + c]);
        // al[e][c] = bf16(P[c][e]): thread (c,q) holds P[c][16q+i]
        #pragma unroll
        for (int i = 0; i < 16; ++i)
            al[(16 * q + i) * APITCH + c] = f2bf(pv[i] * rinv);
        __syncthreads();   // al ready
    }

    // ---------- phase B: apply over this slab's 500 t, barrier-free ----------
    {
        const int c0 = (wave & 1) * 32;
        const int tb = (wave >> 1) * 64;
        // hoist this lane's P^T fragments (row c0+m, all 64 e) into registers
        short8 av[4];
        #pragma unroll
        for (int ks = 0; ks < 4; ++ks)
            av[ks] = *(const short8*)(al + (c0 + m) * APITCH + ks * 16 + 8 * half);

        const float gm = gamma[0];
        float* ob = out + (size_t)b * CC * TT;
        const int t0s = slab * SLABT;

        for (int it = 0; it < 4; ++it) {
            const int t0 = t0s + it * TPB;
            const int ta = t0 + tb + m;            // t for acc0 lane slot
            const int tc = ta + 32;                // t for acc1 lane slot
            f32x16 acc0, acc1;
            #pragma unroll
            for (int z = 0; z < 16; ++z) { acc0[z] = 0.f; acc1[z] = 0.f; }

            #pragma unroll
            for (int ks = 0; ks < 4; ++ks) {
                const int eb = ks * 16 + 8 * half;
                short8 bv0, bv1;
                #pragma unroll
                for (int j = 0; j < 8; ++j) {
                    const float xa = (ta < TT) ? xb[(eb + j) * TT + ta] : 0.f;
                    const float xc = (tc < TT) ? xb[(eb + j) * TT + tc] : 0.f;
                    bv0[j] = f2bf(xa);
                    bv1[j] = f2bf(xc);
                }
                acc0 = __builtin_amdgcn_mfma_f32_32x32x16_bf16(av[ks], bv0, acc0, 0, 0, 0);
                acc1 = __builtin_amdgcn_mfma_f32_32x32x16_bf16(av[ks], bv1, acc1, 0, 0, 0);
            }

            const int tl0 = it * TPB + tb + m;     // local t in [0, 512)
            #pragma unroll
            for (int r = 0; r < 16; ++r) {
                const int row = (r & 3) + 8 * (r >> 2) + 4 * half;
                const int c = c0 + row;
                if (tl0 < SLABT)
                    ob[c * TT + ta] = gm * acc0[r] + xb[c * TT + ta];
                if (tl0 + 32 < SLABT)
                    ob[c * TT + tc] = gm * acc1[r] + xb[c * TT + tc];
            }
        }
    }
}

extern "C" void kernel_launch(void* const* d_in, const int* in_sizes, int n_in,
                              void* d_out, int out_size, void* d_ws, size_t ws_size,
                              hipStream_t stream) {
    const float* x  = (const float*)d_in[0];
    const float* w1 = (const float*)d_in[1];
    const float* b1 = (const float*)d_in[2];
    const float* w2 = (const float*)d_in[3];
    const float* b2 = (const float*)d_in[4];
    const float* gm = (const float*)d_in[5];
    float* out = (float*)d_out;

    float* G_part = (float*)d_ws;
    float* S_part = G_part + GPART_ELEMS;

    hipLaunchKernelGGL(gram_mfma, dim3(BB * SLABS), dim3(256), 0, stream,
                       x, G_part, S_part);
    hipLaunchKernelGGL(softmax_apply, dim3(BB * SLABS), dim3(256), 0, stream,
                       x, w1, b1, w2, b2, G_part, S_part, gm, out);
}

// Round 5
// 157.252 us; speedup vs baseline: 1.1721x; 1.1721x over previous
//
#include <hip/hip_runtime.h>

#define BB 64
#define CC 64
#define TT 4000

// ---- gram geometry ----
#define SLABS 8              // slabs per batch; grid = BB*SLABS = 512
#define TSLAB 250            // staged chunk, padded to 256 t (32 chunks of 8 bf16)
#define SLABT (2 * TSLAB)    // 500 t per block
#define GP_PITCH 264         // shorts per LDS row (16B-aligned rows, chunk 32 = pad)

// ---- apply geometry ----
#define TPB 128
#define XPITCH 132           // floats per xs row (16B aligned)
#define APITCH 72            // shorts per al row (16B aligned)

// ws layout (floats): G_part[8][64][64][64] | S_part[8][64][64]
#define GPART_ELEMS ((size_t)SLABS * BB * CC * CC)

typedef short short8 __attribute__((ext_vector_type(8)));
typedef float f32x16 __attribute__((ext_vector_type(16)));
typedef unsigned u32x4 __attribute__((ext_vector_type(4)));

__device__ __forceinline__ short f2bf(float f) {
    unsigned u = __float_as_uint(f);
    u = (u + 0x7FFFu + ((u >> 16) & 1u)) >> 16;   // round-to-nearest-even
    return (short)u;
}
// packed RNE f32x2 -> bf16x2 (lo = a, hi = b) — one VALU op instead of ~10
__device__ __forceinline__ unsigned cvt_pk(float a, float b) {
    unsigned r;
    asm("v_cvt_pk_bf16_f32 %0, %1, %2" : "=v"(r) : "v"(a), "v"(b));
    return r;
}
__device__ __forceinline__ float bfpair(unsigned u) {   // sum of 2 packed bf16
    return __uint_as_float(u << 16) + __uint_as_float(u & 0xFFFF0000u);
}

// ---- gram helpers ----
__device__ __forceinline__ void stage_load(const float* __restrict__ xb, int t0,
                                           int g, int tid, float4 v[8]) {
    #pragma unroll
    for (int k = 0; k < 8; ++k) {
        const int i = tid + 256 * (g * 8 + k);
        const int row = i >> 6, tq = i & 63;               // t_local = 4*tq
        float4 w = make_float4(0.f, 0.f, 0.f, 0.f);
        if (tq < 62) {
            w = *(const float4*)(xb + row * TT + t0 + 4 * tq);
        } else if (tq == 62) {
            const float* p = xb + row * TT + t0 + 248;
            w.x = p[0]; w.y = p[1];
        }
        v[k] = w;
    }
}
__device__ __forceinline__ void stage_write(short* xs, int g, int tid, const float4 v[8]) {
    #pragma unroll
    for (int k = 0; k < 8; ++k) {
        const int i = tid + 256 * (g * 8 + k);
        const int row = i >> 6, tq = i & 63;
        uint2 sv;
        sv.x = cvt_pk(v[k].x, v[k].y);
        sv.y = cvt_pk(v[k].z, v[k].w);
        const int pc = (tq >> 1) ^ (row & 7);              // swizzled chunk
        *(uint2*)(xs + row * GP_PITCH + pc * 8 + (tq & 1) * 4) = sv;
    }
}
__device__ __forceinline__ float s_partial(const short* xs, int lane, int wave) {
    const short* rowp = xs + lane * GP_PITCH;
    float s = 0.f;
    #pragma unroll
    for (int j = 0; j < 8; ++j) {
        const int pc = (wave * 8 + j) ^ (lane & 7);
        uint2 u0 = *(const uint2*)(rowp + pc * 8);
        uint2 u1 = *(const uint2*)(rowp + pc * 8 + 4);
        s += bfpair(u0.x) + bfpair(u0.y) + bfpair(u1.x) + bfpair(u1.y);
    }
    return s;
}
__device__ __forceinline__ void mfma_tile(const short* xs, int r0, int c0,
                                          int m, int half, f32x16& acc) {
    #pragma unroll
    for (int ks = 0; ks < 16; ++ks) {
        const int ck = ks * 2 + half;                      // logical 8-short chunk of k
        short8 av = *(const short8*)(xs + (r0 + m) * GP_PITCH + (ck ^ (m & 7)) * 8);
        short8 bv = *(const short8*)(xs + (c0 + m) * GP_PITCH + (ck ^ (m & 7)) * 8);
        acc = __builtin_amdgcn_mfma_f32_32x32x16_bf16(av, bv, acc, 0, 0, 0);
    }
}

// G_part[s][b][r][c] = sum_{t in slab} x[b][r][t]*x[b][c][t]; S_part likewise.
// Double-buffered: chunk-1 global loads issued before chunk-0 compute (T14).
__global__ __launch_bounds__(256)
void gram_mfma(const float* __restrict__ x, float* __restrict__ G_part,
               float* __restrict__ S_part) {
    __shared__ short xs[2][CC * GP_PITCH];   // 2 x 33.8 KB bf16
    __shared__ float sred[4 * 64];
    const int b    = blockIdx.x / SLABS;
    const int slab = blockIdx.x % SLABS;
    const int tid  = threadIdx.x;
    const int lane = tid & 63;
    const int wave = tid >> 6;
    const float* xb = x + (size_t)b * CC * TT;

    const int r0 = (wave >> 1) * 32, c0 = (wave & 1) * 32;
    const int m = lane & 31, half = lane >> 5;
    f32x16 acc;
    #pragma unroll
    for (int z = 0; z < 16; ++z) acc[z] = 0.f;

    const int t0a = slab * SLABT, t0b = t0a + TSLAB;

    // stage chunk 0 into xs[0]
    {
        float4 v[8];
        stage_load(xb, t0a, 0, tid, v);
        stage_write(xs[0], 0, tid, v);
        stage_load(xb, t0a, 1, tid, v);
        stage_write(xs[0], 1, tid, v);
    }
    __syncthreads();

    // prefetch chunk 1 into registers (latency hides under chunk-0 compute)
    float4 p0[8], p1[8];
    stage_load(xb, t0b, 0, tid, p0);
    stage_load(xb, t0b, 1, tid, p1);

    // compute chunk 0
    float s_acc = s_partial(xs[0], lane, wave);
    mfma_tile(xs[0], r0, c0, m, half, acc);

    // write chunk 1 (waits on the prefetch loads here)
    stage_write(xs[1], 0, tid, p0);
    stage_write(xs[1], 1, tid, p1);
    __syncthreads();

    // compute chunk 1
    s_acc += s_partial(xs[1], lane, wave);
    mfma_tile(xs[1], r0, c0, m, half, acc);

    sred[wave * 64 + lane] = s_acc;
    __syncthreads();
    if (tid < 64) {
        float s = sred[tid] + sred[64 + tid] + sred[128 + tid] + sred[192 + tid];
        S_part[(slab * BB + b) * CC + tid] = s;
    }
    float* gp = G_part + ((size_t)slab * BB + b) * (CC * CC);
    #pragma unroll
    for (int r = 0; r < 16; ++r) {
        const int row = (r & 3) + 8 * (r >> 2) + 4 * half;
        gp[(r0 + row) * CC + (c0 + m)] = acc[r];
    }
}

// Kernel 2: 512 blocks = (slab, b). Redundant per-block softmax into LDS al
// (al[X][Y] = attention[Y][X], bf16), then LDS-staged apply with a register
// double-buffer: tile it+1's global loads are issued right after tile it's
// LDS-write barrier and consumed a full compute-phase later (T14).
__global__ __launch_bounds__(256)
void softmax_apply(const float* __restrict__ x,
                   const float* __restrict__ w1, const float* __restrict__ b1,
                   const float* __restrict__ w2, const float* __restrict__ b2,
                   const float* __restrict__ G_part, const float* __restrict__ S_part,
                   const float* __restrict__ gamma, float* __restrict__ out) {
    __shared__ float Es[64 * 65];         // 16.6 KB
    __shared__ float xsbuf[CC * XPITCH];  // 33.8 KB fp32 apply tile
    __shared__ short al[CC * APITCH];     // 9.2 KB bf16
    __shared__ float red[3 * 256];
    __shared__ float Sb[64];
    const int tid  = threadIdx.x;
    const int lane = tid & 63, wave = tid >> 6;
    const int b    = blockIdx.x & 63;
    const int slab = blockIdx.x >> 6;
    const float* xb = x + (size_t)b * CC * TT;
    const int m = lane & 31, half = lane >> 5;

    // ---------- phase A: softmax for batch b ----------
    {
        #pragma unroll
        for (int j4 = 0; j4 < 4; ++j4) {
            const int jj = tid + 256 * j4;                 // float4 index 0..1023
            float4 s = make_float4(0.f, 0.f, 0.f, 0.f);
            #pragma unroll
            for (int sl = 0; sl < SLABS; ++sl) {
                const float4 g = *(const float4*)(G_part + ((size_t)sl * BB + b) * 4096 + 4 * jj);
                s.x += g.x; s.y += g.y; s.z += g.z; s.w += g.w;
            }
            const int row = jj >> 4, col = (jj & 15) * 4;
            float* e = Es + row * 65 + col;
            e[0] = s.x; e[1] = s.y; e[2] = s.z; e[3] = s.w;
        }
        if (tid < 64) {
            float s = 0.f;
            #pragma unroll
            for (int sl = 0; sl < SLABS; ++sl)
                s += S_part[(sl * BB + b) * CC + tid];
            Sb[tid] = s;
        }
        float A = 0.f, Bc = 0.f, Be = 0.f, Cc = 0.f;
        #pragma unroll
        for (int j = 0; j < 8; ++j) {
            float a1 = w1[j], a2 = w2[j], q1 = b1[j], q2 = b2[j];
            A += a1 * a2; Bc += a1 * q2; Be += q1 * a2; Cc += q1 * q2;
        }
        Cc *= (float)TT;
        __syncthreads();

        const int c = tid & 63, q = tid >> 6;
        const float sc = Sb[c];
        float ev[16], mn = 1e30f, mx = -1e30f;
        #pragma unroll
        for (int i = 0; i < 16; ++i) {
            const int e = 16 * q + i;
            float en = A * Es[c * 65 + e] + Bc * sc + Be * Sb[e] + Cc;
            ev[i] = en;
            mn = fminf(mn, en); mx = fmaxf(mx, en);
        }
        red[q * 64 + c] = mn; red[256 + q * 64 + c] = mx;
        __syncthreads();
        mn = fminf(fminf(red[c], red[64 + c]), fminf(red[128 + c], red[192 + c]));
        mx = fmaxf(fmaxf(red[256 + c], red[320 + c]), fmaxf(red[384 + c], red[448 + c]));
        const float ninv = 1.f / (mx - mn + 1e-8f);
        float pv[16], ls = 0.f;
        #pragma unroll
        for (int i = 0; i < 16; ++i) {
            float p = __expf((ev[i] - mn) * ninv);
            pv[i] = p; ls += p;
        }
        red[512 + q * 64 + c] = ls;
        __syncthreads();
        const float rinv = 1.f / (red[512 + c] + red[576 + c] + red[640 + c] + red[704 + c]);
        // al[e][c] = bf16(attention[c][e]); read back as A[c][e] rows
        #pragma unroll
        for (int i = 0; i < 16; ++i)
            al[(16 * q + i) * APITCH + c] = f2bf(pv[i] * rinv);
        __syncthreads();   // al ready
    }

    // ---------- phase B: apply over this slab's 500 t, pipelined ----------
    {
        const int c0 = (wave & 1) * 32;
        const int tb = (wave >> 1) * 64;
        short8 av[4];
        #pragma unroll
        for (int ks = 0; ks < 4; ++ks)
            av[ks] = *(const short8*)(al + (c0 + m) * APITCH + ks * 16 + 8 * half);

        const float gm = gamma[0];
        float* ob = out + (size_t)b * CC * TT;
        const int t0s = slab * SLABT;
        const int ie = tid >> 5, ip = tid & 31;            // staging coords

        float4 v[8];
        // load tile 0
        #pragma unroll
        for (int k = 0; k < 8; ++k) {
            const int i = tid + 256 * k;
            const int e = i >> 5, p = i & 31;
            const int t = t0s + 4 * p;
            v[k] = make_float4(0.f, 0.f, 0.f, 0.f);
            if (t < TT) v[k] = *(const float4*)(xb + e * TT + t);
        }

        for (int it = 0; it < 4; ++it) {
            // write tile it from registers (previous compute done: barrier below)
            #pragma unroll
            for (int k = 0; k < 8; ++k) {
                const int i = tid + 256 * k;
                const int e = i >> 5, p = i & 31;
                *(float4*)(xsbuf + e * XPITCH + 4 * p) = v[k];
            }
            __syncthreads();
            // issue tile it+1's loads NOW; consumed after the compute below
            if (it < 3) {
                const int t0n = t0s + (it + 1) * TPB;
                #pragma unroll
                for (int k = 0; k < 8; ++k) {
                    const int i = tid + 256 * k;
                    const int e = i >> 5, p = i & 31;
                    const int t = t0n + 4 * p;
                    v[k] = make_float4(0.f, 0.f, 0.f, 0.f);
                    if (t < TT) v[k] = *(const float4*)(xb + e * TT + t);
                }
            }

            f32x16 acc0, acc1;
            #pragma unroll
            for (int z = 0; z < 16; ++z) { acc0[z] = 0.f; acc1[z] = 0.f; }
            #pragma unroll
            for (int ks = 0; ks < 4; ++ks) {
                const int eb = ks * 16 + 8 * half;
                u32x4 pk0, pk1;
                #pragma unroll
                for (int j2 = 0; j2 < 4; ++j2) {
                    const float* col = xsbuf + (eb + 2 * j2) * XPITCH;
                    pk0[j2] = cvt_pk(col[tb + m],      col[XPITCH + tb + m]);
                    pk1[j2] = cvt_pk(col[tb + 32 + m], col[XPITCH + tb + 32 + m]);
                }
                acc0 = __builtin_amdgcn_mfma_f32_32x32x16_bf16(
                    av[ks], __builtin_bit_cast(short8, pk0), acc0, 0, 0, 0);
                acc1 = __builtin_amdgcn_mfma_f32_32x32x16_bf16(
                    av[ks], __builtin_bit_cast(short8, pk1), acc1, 0, 0, 0);
            }

            const int t0  = t0s + it * TPB;
            const int ta  = t0 + tb + m, tc = ta + 32;
            const int tl0 = it * TPB + tb + m;
            #pragma unroll
            for (int r = 0; r < 16; ++r) {
                const int row = (r & 3) + 8 * (r >> 2) + 4 * half;
                const int c = c0 + row;
                if (tl0 < SLABT)
                    ob[c * TT + ta] = gm * acc0[r] + xsbuf[c * XPITCH + tb + m];
                if (tl0 + 32 < SLABT)
                    ob[c * TT + tc] = gm * acc1[r] + xsbuf[c * XPITCH + tb + 32 + m];
            }
            __syncthreads();   // xsbuf free for next tile's writes
        }
    }
}

extern "C" void kernel_launch(void* const* d_in, const int* in_sizes, int n_in,
                              void* d_out, int out_size, void* d_ws, size_t ws_size,
                              hipStream_t stream) {
    const float* x  = (const float*)d_in[0];
    const float* w1 = (const float*)d_in[1];
    const float* b1 = (const float*)d_in[2];
    const float* w2 = (const float*)d_in[3];
    const float* b2 = (const float*)d_in[4];
    const float* gm = (const float*)d_in[5];
    float* out = (float*)d_out;

    float* G_part = (float*)d_ws;
    float* S_part = G_part + GPART_ELEMS;

    hipLaunchKernelGGL(gram_mfma, dim3(BB * SLABS), dim3(256), 0, stream,
                       x, G_part, S_part);
    hipLaunchKernelGGL(softmax_apply, dim3(BB * SLABS), dim3(256), 0, stream,
                       x, w1, b1, w2, b2, G_part, S_part, gm, out);
}